// Round 1
// baseline (628.910 us; speedup 1.0000x reference)
//
#include <hip/hip_runtime.h>
#include <hip/hip_bf16.h>

#define S_LEN 2048
#define NH 16
#define HD 64
#define DM 1024

typedef float f32x4 __attribute__((ext_vector_type(4)));
typedef __bf16 bf16x8 __attribute__((ext_vector_type(8)));

__device__ __forceinline__ unsigned short f2bf(float f) {
  union { float f; unsigned u; } v; v.f = f;
  unsigned r = v.u + 0x7fffu + ((v.u >> 16) & 1u);
  return (unsigned short)(r >> 16);
}

__device__ __forceinline__ void load_lds16(const void* g, void* l) {
  __builtin_amdgcn_global_load_lds((const __attribute__((address_space(1))) void*)g,
                                   (__attribute__((address_space(3))) void*)l, 16, 0, 0);
}

// fp32 -> bf16 rowmajor convert (4 elems/thread)
__global__ __launch_bounds__(256) void cvt_kernel(const float* __restrict__ in,
                                                  unsigned short* __restrict__ out) {
  int i = blockIdx.x * 256 + threadIdx.x;
  float4 v = reinterpret_cast<const float4*>(in)[i];
  ushort4 o;
  o.x = f2bf(v.x); o.y = f2bf(v.y); o.z = f2bf(v.z); o.w = f2bf(v.w);
  reinterpret_cast<ushort4*>(out)[i] = o;
}

// W [1024][1024] fp32 -> Wt [n][k] bf16 (transpose + convert)
__global__ __launch_bounds__(256) void wtrans_kernel(const float* __restrict__ W,
                                                     unsigned short* __restrict__ Wt) {
  __shared__ float t[32][33];
  int bx = blockIdx.x * 32;  // n base
  int by = blockIdx.y * 32;  // k base
  int tx = threadIdx.x & 31, ty = threadIdx.x >> 5;
  for (int i = ty; i < 32; i += 8) t[i][tx] = W[(size_t)(by + i) * DM + bx + tx];
  __syncthreads();
  for (int i = ty; i < 32; i += 8) Wt[(size_t)(bx + i) * DM + by + tx] = f2bf(t[tx][i]);
}

// C = A[4096x1024] @ Bt[1024x1024]^T + bias.  128x128 tile, BK=32, 4 waves.
// MODE 0: bf16 head-major out [B,H,S,64]; MODE 1: bf16 transposed [B,H,64,S]; MODE 2: fp32 rowmajor.
template <int MODE>
__global__ __launch_bounds__(256) void gemm128(const unsigned short* __restrict__ A,
                                               const unsigned short* __restrict__ Bt,
                                               const float* __restrict__ bias,
                                               void* __restrict__ outp) {
  constexpr int K = 1024;
  constexpr int N = 1024;
  __shared__ unsigned short Al[128 * 32];
  __shared__ unsigned short Bl[128 * 32];
  const int tid = threadIdx.x;
  const int w = tid >> 6, l = tid & 63;
  const int m0 = blockIdx.x * 128, n0 = blockIdx.y * 128;
  const int wr = (w >> 1) * 64, wc = (w & 1) * 64;
  const int lr = l & 15, lk = l >> 4;
  f32x4 acc[4][4] = {};
  for (int kt = 0; kt < K; kt += 32) {
#pragma unroll
    for (int i = 0; i < 2; ++i) {
      int seg = i * 256 + tid;
      int row = seg >> 2, ks = (seg & 3) * 8;
      load_lds16(A + (size_t)(m0 + row) * K + kt + ks, Al + seg * 8);
      load_lds16(Bt + (size_t)(n0 + row) * K + kt + ks, Bl + seg * 8);
    }
    __syncthreads();
    bf16x8 af[4], bfr[4];
#pragma unroll
    for (int t = 0; t < 4; ++t) af[t] = *(const bf16x8*)(Al + (wr + t * 16 + lr) * 32 + lk * 8);
#pragma unroll
    for (int t = 0; t < 4; ++t) bfr[t] = *(const bf16x8*)(Bl + (wc + t * 16 + lr) * 32 + lk * 8);
#pragma unroll
    for (int i = 0; i < 4; ++i)
#pragma unroll
      for (int j = 0; j < 4; ++j)
        acc[i][j] = __builtin_amdgcn_mfma_f32_16x16x32_bf16(af[i], bfr[j], acc[i][j], 0, 0, 0);
    __syncthreads();
  }
  const int drow = lk * 4, dcol = lr;
  if (MODE == 2) {
    float* C = (float*)outp;
#pragma unroll
    for (int i = 0; i < 4; ++i)
#pragma unroll
      for (int j = 0; j < 4; ++j) {
        int n = n0 + wc + j * 16 + dcol;
        float bv = bias[n];
#pragma unroll
        for (int r = 0; r < 4; ++r) {
          int m = m0 + wr + i * 16 + drow + r;
          C[(size_t)m * N + n] = acc[i][j][r] + bv;
        }
      }
  } else if (MODE == 0) {
    unsigned short* C = (unsigned short*)outp;
#pragma unroll
    for (int i = 0; i < 4; ++i)
#pragma unroll
      for (int j = 0; j < 4; ++j) {
        int n = n0 + wc + j * 16 + dcol;
        float bv = bias[n];
        int h = n >> 6, d = n & 63;
#pragma unroll
        for (int r = 0; r < 4; ++r) {
          int m = m0 + wr + i * 16 + drow + r;
          int b = m >> 11, s = m & 2047;
          C[((size_t)(b * NH + h) * S_LEN + s) * HD + d] = f2bf(acc[i][j][r] + bv);
        }
      }
  } else {  // MODE 1: V transposed [B,H,64,S]
    unsigned short* C = (unsigned short*)outp;
#pragma unroll
    for (int i = 0; i < 4; ++i) {
      int m = m0 + wr + i * 16 + drow;  // rows m..m+3 same b (16-aligned)
      int b = m >> 11, s = m & 2047;
#pragma unroll
      for (int j = 0; j < 4; ++j) {
        int n = n0 + wc + j * 16 + dcol;
        float bv = bias[n];
        int h = n >> 6, d = n & 63;
        ushort4 o;
        o.x = f2bf(acc[i][j][0] + bv);
        o.y = f2bf(acc[i][j][1] + bv);
        o.z = f2bf(acc[i][j][2] + bv);
        o.w = f2bf(acc[i][j][3] + bv);
        *reinterpret_cast<ushort4*>(C + ((size_t)(b * NH + h) * HD + d) * S_LEN + s) = o;
      }
    }
  }
}

// Fused QK^T + softmax + attn-write + PV. One block = 16 q-rows of one (b,h).
// Wave w owns k-columns [w*512, w*512+512). Scores live in registers (32 x f32x4).
__global__ __launch_bounds__(256) void attn_kernel(const unsigned short* __restrict__ Qh,
                                                   const unsigned short* __restrict__ Kh,
                                                   const unsigned short* __restrict__ Vt,
                                                   const unsigned char* __restrict__ mask,
                                                   float* __restrict__ attn_out,
                                                   unsigned short* __restrict__ ctx) {
  __shared__ unsigned short P[16][2056];  // padded: +8 bf16 per row to spread banks
  __shared__ float redmax[16][4];
  __shared__ float redsum[16][4];
  const int tid = threadIdx.x;
  const int w = tid >> 6, l = tid & 63;
  const int q0 = blockIdx.x * 16;
  const int bh = blockIdx.y;
  const int b = bh >> 4, h = bh & 15;
  const int lr = l & 15, lk = l >> 4;
  const int drow = lk * 4, dcol = lr;
  const int c0 = w * 512;
  const unsigned short* Qbh = Qh + (size_t)bh * S_LEN * HD;
  const unsigned short* Kbh = Kh + (size_t)bh * S_LEN * HD;
  const unsigned short* Vbh = Vt + (size_t)bh * HD * S_LEN;
  const unsigned char* mb = mask + (size_t)b * S_LEN * S_LEN;

  bf16x8 aq0 = *(const bf16x8*)(Qbh + (q0 + lr) * HD + lk * 8);
  bf16x8 aq1 = *(const bf16x8*)(Qbh + (q0 + lr) * HD + 32 + lk * 8);

  f32x4 acc[32];
#pragma unroll
  for (int t = 0; t < 32; ++t) {
    const unsigned short* kp = Kbh + (size_t)(c0 + t * 16 + lr) * HD + lk * 8;
    bf16x8 b0 = *(const bf16x8*)kp;
    bf16x8 b1 = *(const bf16x8*)(kp + 32);
    f32x4 a = {};
    a = __builtin_amdgcn_mfma_f32_16x16x32_bf16(aq0, b0, a, 0, 0, 0);
    a = __builtin_amdgcn_mfma_f32_16x16x32_bf16(aq1, b1, a, 0, 0, 0);
    acc[t] = a;
  }

  // wave-level fast-path check on the mask region [q0,q0+16) x [c0,c0+512)
  int anymask;
  {
    const unsigned char* mp = mb + (size_t)(q0 + (l >> 2)) * S_LEN + c0 + (l & 3) * 128;
    unsigned orv = 0;
#pragma unroll
    for (int i = 0; i < 8; ++i) {
      uint4 v = *(const uint4*)(mp + i * 16);
      orv |= v.x | v.y | v.z | v.w;
    }
    anymask = __any(orv != 0);
  }

  const float sc = 0.125f;  // 1/sqrt(64)
  float rmax[4] = {-3e38f, -3e38f, -3e38f, -3e38f};
  if (anymask) {
#pragma unroll
    for (int t = 0; t < 32; ++t)
#pragma unroll
      for (int r = 0; r < 4; ++r) {
        float v = acc[t][r] * sc;
        if (mb[(size_t)(q0 + drow + r) * S_LEN + c0 + t * 16 + dcol]) v = -1e9f;
        acc[t][r] = v;
        rmax[r] = fmaxf(rmax[r], v);
      }
  } else {
#pragma unroll
    for (int t = 0; t < 32; ++t)
#pragma unroll
      for (int r = 0; r < 4; ++r) {
        float v = acc[t][r] * sc;
        acc[t][r] = v;
        rmax[r] = fmaxf(rmax[r], v);
      }
  }
#pragma unroll
  for (int off = 1; off < 16; off <<= 1)
#pragma unroll
    for (int r = 0; r < 4; ++r) rmax[r] = fmaxf(rmax[r], __shfl_xor(rmax[r], off, 64));
  if (dcol == 0) {
#pragma unroll
    for (int r = 0; r < 4; ++r) redmax[drow + r][w] = rmax[r];
  }
  __syncthreads();
  float rowmax[4];
#pragma unroll
  for (int r = 0; r < 4; ++r) {
    float m = fmaxf(fmaxf(redmax[drow + r][0], redmax[drow + r][1]),
                    fmaxf(redmax[drow + r][2], redmax[drow + r][3]));
    rowmax[r] = m;
  }
  float rowsum[4] = {0.f, 0.f, 0.f, 0.f};
#pragma unroll
  for (int t = 0; t < 32; ++t)
#pragma unroll
    for (int r = 0; r < 4; ++r) {
      float p = __expf(acc[t][r] - rowmax[r]);
      acc[t][r] = p;
      rowsum[r] += p;
    }
#pragma unroll
  for (int off = 1; off < 16; off <<= 1)
#pragma unroll
    for (int r = 0; r < 4; ++r) rowsum[r] += __shfl_xor(rowsum[r], off, 64);
  if (dcol == 0) {
#pragma unroll
    for (int r = 0; r < 4; ++r) redsum[drow + r][w] = rowsum[r];
  }
  __syncthreads();
  float inv[4];
#pragma unroll
  for (int r = 0; r < 4; ++r) {
    float s = redsum[drow + r][0] + redsum[drow + r][1] + redsum[drow + r][2] + redsum[drow + r][3];
    inv[r] = 1.0f / s;
  }
  float* arow = attn_out + ((size_t)bh * S_LEN + q0) * S_LEN;
#pragma unroll
  for (int t = 0; t < 32; ++t) {
    int k = c0 + t * 16 + dcol;
#pragma unroll
    for (int r = 0; r < 4; ++r) {
      float p = acc[t][r] * inv[r];
      arow[(size_t)(drow + r) * S_LEN + k] = p;
      P[drow + r][k] = f2bf(p);
    }
  }
  __syncthreads();
  // PV: ctx[16 x 64] ; wave w owns d-columns [w*16, w*16+16)
  const int n0 = w * 16;
  f32x4 av = {};
#pragma unroll
  for (int ks = 0; ks < 64; ++ks) {
    bf16x8 pa = *(const bf16x8*)(&P[lr][ks * 32 + lk * 8]);
    bf16x8 vb = *(const bf16x8*)(Vbh + (size_t)(n0 + lr) * S_LEN + ks * 32 + lk * 8);
    av = __builtin_amdgcn_mfma_f32_16x16x32_bf16(pa, vb, av, 0, 0, 0);
  }
#pragma unroll
  for (int r = 0; r < 4; ++r) {
    int s = q0 + drow + r;
    ctx[(size_t)(b * S_LEN + s) * DM + h * HD + n0 + dcol] = f2bf(av[r]);
  }
}

// residual + LayerNorm: out = LN(pre + Qin) * gamma + beta, rows of 1024
__global__ __launch_bounds__(256) void ln_kernel(const float* __restrict__ pre,
                                                 const float* __restrict__ Qin,
                                                 const float* __restrict__ gamma,
                                                 const float* __restrict__ beta,
                                                 float* __restrict__ out) {
  __shared__ float red[4];
  const int row = blockIdx.x;
  const int tid = threadIdx.x;
  const int wv = tid >> 6, l = tid & 63;
  const float4 a = reinterpret_cast<const float4*>(pre + (size_t)row * DM)[tid];
  const float4 q = reinterpret_cast<const float4*>(Qin + (size_t)row * DM)[tid];
  float x0 = a.x + q.x, x1 = a.y + q.y, x2 = a.z + q.z, x3 = a.w + q.w;
  float s = x0 + x1 + x2 + x3;
#pragma unroll
  for (int off = 32; off >= 1; off >>= 1) s += __shfl_xor(s, off, 64);
  if (l == 0) red[wv] = s;
  __syncthreads();
  float mean = (red[0] + red[1] + red[2] + red[3]) * (1.0f / 1024.0f);
  __syncthreads();
  float d0 = x0 - mean, d1 = x1 - mean, d2 = x2 - mean, d3 = x3 - mean;
  float s2 = d0 * d0 + d1 * d1 + d2 * d2 + d3 * d3;
#pragma unroll
  for (int off = 32; off >= 1; off >>= 1) s2 += __shfl_xor(s2, off, 64);
  if (l == 0) red[wv] = s2;
  __syncthreads();
  float var = (red[0] + red[1] + red[2] + red[3]) * (1.0f / 1024.0f);
  float rstd = rsqrtf(var + 1e-5f);
  const float4 g = reinterpret_cast<const float4*>(gamma)[tid];
  const float4 bt = reinterpret_cast<const float4*>(beta)[tid];
  float4 o;
  o.x = d0 * rstd * g.x + bt.x;
  o.y = d1 * rstd * g.y + bt.y;
  o.z = d2 * rstd * g.z + bt.z;
  o.w = d3 * rstd * g.w + bt.w;
  reinterpret_cast<float4*>(out + (size_t)row * DM)[tid] = o;
}

extern "C" void kernel_launch(void* const* d_in, const int* in_sizes, int n_in,
                              void* d_out, int out_size, void* d_ws, size_t ws_size,
                              hipStream_t stream) {
  const float* Qi = (const float*)d_in[0];
  const float* Ki = (const float*)d_in[1];
  const float* Vi = (const float*)d_in[2];
  const unsigned char* mask = (const unsigned char*)d_in[3];
  const float* Wq = (const float*)d_in[4];
  const float* bq = (const float*)d_in[5];
  const float* Wk = (const float*)d_in[6];
  const float* bk = (const float*)d_in[7];
  const float* Wv = (const float*)d_in[8];
  const float* bv = (const float*)d_in[9];
  const float* Wo = (const float*)d_in[10];
  const float* bo = (const float*)d_in[11];
  const float* gamma = (const float*)d_in[12];
  const float* beta = (const float*)d_in[13];

  char* ws = (char*)d_ws;
  unsigned short* Qb = (unsigned short*)(ws);            // [4096][1024] bf16
  unsigned short* Kb = Qb + 4194304;
  unsigned short* Vb = Qb + 2 * 4194304;
  unsigned short* Wtq = (unsigned short*)(ws + 25165824);  // [n][k] bf16 x4
  unsigned short* Wtk = Wtq + 1048576;
  unsigned short* Wtv = Wtq + 2 * 1048576;
  unsigned short* Wto = Wtq + 3 * 1048576;
  unsigned short* Qhd = (unsigned short*)(ws + 33554432);  // [B,H,S,64] bf16
  unsigned short* Khd = (unsigned short*)(ws + 41943040);  // [B,H,S,64] bf16
  unsigned short* Vtd = (unsigned short*)(ws + 50331648);  // [B,H,64,S] bf16
  unsigned short* ctx = (unsigned short*)(ws);             // reuse Qb region
  float* preLN = (float*)(ws + 8388608);                   // reuse Kb/Vb region

  float* out0 = (float*)d_out;
  float* attn = out0 + 4194304;

  cvt_kernel<<<4096, 256, 0, stream>>>(Qi, Qb);
  cvt_kernel<<<4096, 256, 0, stream>>>(Ki, Kb);
  cvt_kernel<<<4096, 256, 0, stream>>>(Vi, Vb);
  dim3 tg(32, 32);
  wtrans_kernel<<<tg, 256, 0, stream>>>(Wq, Wtq);
  wtrans_kernel<<<tg, 256, 0, stream>>>(Wk, Wtk);
  wtrans_kernel<<<tg, 256, 0, stream>>>(Wv, Wtv);
  wtrans_kernel<<<tg, 256, 0, stream>>>(Wo, Wto);
  dim3 gg(32, 8);
  gemm128<0><<<gg, 256, 0, stream>>>(Qb, Wtq, bq, Qhd);
  gemm128<0><<<gg, 256, 0, stream>>>(Kb, Wtk, bk, Khd);
  gemm128<1><<<gg, 256, 0, stream>>>(Vb, Wtv, bv, Vtd);
  dim3 ag(128, 32);
  attn_kernel<<<ag, 256, 0, stream>>>(Qhd, Khd, Vtd, mask, attn, ctx);
  gemm128<2><<<gg, 256, 0, stream>>>(ctx, Wto, bo, preLN);
  ln_kernel<<<4096, 256, 0, stream>>>(preLN, Qi, gamma, beta, out0);
}

// Round 2
// 507.834 us; speedup vs baseline: 1.2384x; 1.2384x over previous
//
#include <hip/hip_runtime.h>
#include <hip/hip_bf16.h>

#define S_LEN 2048
#define NH 16
#define HD 64
#define DM 1024

typedef float f32x4 __attribute__((ext_vector_type(4)));
typedef __bf16 bf16x8 __attribute__((ext_vector_type(8)));

__device__ __forceinline__ unsigned short f2bf(float f) {
  union { float f; unsigned u; } v; v.f = f;
  unsigned r = v.u + 0x7fffu + ((v.u >> 16) & 1u);
  return (unsigned short)(r >> 16);
}

__device__ __forceinline__ unsigned pack2bf(float lo, float hi) {
  return (unsigned)f2bf(lo) | ((unsigned)f2bf(hi) << 16);
}

__device__ __forceinline__ void load_lds16(const void* g, void* l) {
  __builtin_amdgcn_global_load_lds((const __attribute__((address_space(1))) void*)g,
                                   (__attribute__((address_space(3))) void*)l, 16, 0, 0);
}

// fp32 -> bf16 rowmajor convert (4 elems/thread)
__global__ __launch_bounds__(256) void cvt_kernel(const float* __restrict__ in,
                                                  unsigned short* __restrict__ out) {
  int i = blockIdx.x * 256 + threadIdx.x;
  float4 v = reinterpret_cast<const float4*>(in)[i];
  ushort4 o;
  o.x = f2bf(v.x); o.y = f2bf(v.y); o.z = f2bf(v.z); o.w = f2bf(v.w);
  reinterpret_cast<ushort4*>(out)[i] = o;
}

// W [1024][1024] fp32 -> Wt [n][k] bf16 (transpose + convert)
__global__ __launch_bounds__(256) void wtrans_kernel(const float* __restrict__ W,
                                                     unsigned short* __restrict__ Wt) {
  __shared__ float t[32][33];
  int bx = blockIdx.x * 32;  // n base
  int by = blockIdx.y * 32;  // k base
  int tx = threadIdx.x & 31, ty = threadIdx.x >> 5;
  for (int i = ty; i < 32; i += 8) t[i][tx] = W[(size_t)(by + i) * DM + bx + tx];
  __syncthreads();
  for (int i = ty; i < 32; i += 8) Wt[(size_t)(bx + i) * DM + by + tx] = f2bf(t[tx][i]);
}

// C = A[4096x1024] @ Bt[1024x1024]^T + bias.  128x128 tile, BK=32, 4 waves.
// MODE 0: bf16 head-major out [B,H,S,64]; MODE 1: bf16 transposed [B,H,64,S]; MODE 2: fp32 rowmajor.
template <int MODE>
__global__ __launch_bounds__(256) void gemm128(const unsigned short* __restrict__ A,
                                               const unsigned short* __restrict__ Bt,
                                               const float* __restrict__ bias,
                                               void* __restrict__ outp) {
  constexpr int K = 1024;
  constexpr int N = 1024;
  __shared__ unsigned short Al[128 * 32];
  __shared__ unsigned short Bl[128 * 32];
  const int tid = threadIdx.x;
  const int w = tid >> 6, l = tid & 63;
  const int m0 = blockIdx.x * 128, n0 = blockIdx.y * 128;
  const int wr = (w >> 1) * 64, wc = (w & 1) * 64;
  const int lr = l & 15, lk = l >> 4;
  f32x4 acc[4][4] = {};
  for (int kt = 0; kt < K; kt += 32) {
#pragma unroll
    for (int i = 0; i < 2; ++i) {
      int seg = i * 256 + tid;
      int row = seg >> 2, ks = (seg & 3) * 8;
      load_lds16(A + (size_t)(m0 + row) * K + kt + ks, Al + seg * 8);
      load_lds16(Bt + (size_t)(n0 + row) * K + kt + ks, Bl + seg * 8);
    }
    __syncthreads();
    bf16x8 af[4], bfr[4];
#pragma unroll
    for (int t = 0; t < 4; ++t) af[t] = *(const bf16x8*)(Al + (wr + t * 16 + lr) * 32 + lk * 8);
#pragma unroll
    for (int t = 0; t < 4; ++t) bfr[t] = *(const bf16x8*)(Bl + (wc + t * 16 + lr) * 32 + lk * 8);
#pragma unroll
    for (int i = 0; i < 4; ++i)
#pragma unroll
      for (int j = 0; j < 4; ++j)
        acc[i][j] = __builtin_amdgcn_mfma_f32_16x16x32_bf16(af[i], bfr[j], acc[i][j], 0, 0, 0);
    __syncthreads();
  }
  const int drow = lk * 4, dcol = lr;
  if (MODE == 2) {
    float* C = (float*)outp;
#pragma unroll
    for (int i = 0; i < 4; ++i)
#pragma unroll
      for (int j = 0; j < 4; ++j) {
        int n = n0 + wc + j * 16 + dcol;
        float bv = bias[n];
#pragma unroll
        for (int r = 0; r < 4; ++r) {
          int m = m0 + wr + i * 16 + drow + r;
          C[(size_t)m * N + n] = acc[i][j][r] + bv;
        }
      }
  } else if (MODE == 0) {
    unsigned short* C = (unsigned short*)outp;
#pragma unroll
    for (int i = 0; i < 4; ++i)
#pragma unroll
      for (int j = 0; j < 4; ++j) {
        int n = n0 + wc + j * 16 + dcol;
        float bv = bias[n];
        int h = n >> 6, d = n & 63;
#pragma unroll
        for (int r = 0; r < 4; ++r) {
          int m = m0 + wr + i * 16 + drow + r;
          int b = m >> 11, s = m & 2047;
          C[((size_t)(b * NH + h) * S_LEN + s) * HD + d] = f2bf(acc[i][j][r] + bv);
        }
      }
  } else {  // MODE 1: V transposed [B,H,64,S]
    unsigned short* C = (unsigned short*)outp;
#pragma unroll
    for (int i = 0; i < 4; ++i) {
      int m = m0 + wr + i * 16 + drow;  // rows m..m+3 same b (16-aligned)
      int b = m >> 11, s = m & 2047;
#pragma unroll
      for (int j = 0; j < 4; ++j) {
        int n = n0 + wc + j * 16 + dcol;
        float bv = bias[n];
        int h = n >> 6, d = n & 63;
        ushort4 o;
        o.x = f2bf(acc[i][j][0] + bv);
        o.y = f2bf(acc[i][j][1] + bv);
        o.z = f2bf(acc[i][j][2] + bv);
        o.w = f2bf(acc[i][j][3] + bv);
        *reinterpret_cast<ushort4*>(C + ((size_t)(b * NH + h) * HD + d) * S_LEN + s) = o;
      }
    }
  }
}

// Fused QK^T + softmax + attn-write + PV, swapped-operand layout.
// Block = 512 threads (8 waves), 16 q-rows of one (b,h). Wave w owns k-slice
// [w*256, w*256+256). Swapped MFMA (A=K, B=Q) puts q on the lane-col axis:
// lane (lr,lk) holds S[k = c0+t*16+lk*4+r][q = q0+lr] -> softmax over k is
// in-lane + shfl_xor(16,32); attn store is float4/lane; P stays in registers
// (packed bf16), PV A-frags assembled via __shfl; per-wave partial PV reduced
// through a 32KB LDS buffer.
__global__ __launch_bounds__(512, 4) void attn_kernel(const unsigned short* __restrict__ Qh,
                                                      const unsigned short* __restrict__ Kh,
                                                      const unsigned short* __restrict__ Vt,
                                                      const unsigned char* __restrict__ mask,
                                                      float* __restrict__ attn_out,
                                                      unsigned short* __restrict__ ctx) {
  __shared__ float wredmax[8][16];
  __shared__ float wredsum[8][16];
  __shared__ float ctxpart[8][1024];
  const int tid = threadIdx.x;
  const int w = tid >> 6, l = tid & 63;
  const int lr = l & 15, lk = l >> 4;
  const int q0 = blockIdx.x * 16;
  const int bh = blockIdx.y;
  const int b = bh >> 4, h = bh & 15;
  const int c0 = w * 256;
  const unsigned short* Qbh = Qh + (size_t)bh * S_LEN * HD;
  const unsigned short* Kbh = Kh + (size_t)bh * S_LEN * HD;
  const unsigned short* Vbh = Vt + (size_t)bh * HD * S_LEN;
  const unsigned char* mb = mask + (size_t)b * S_LEN * S_LEN;

  // wave-level mask fast-path check on [q0,q0+16) x [c0,c0+256)
  int anymask;
  {
    const unsigned char* mp = mb + (size_t)(q0 + (l >> 2)) * S_LEN + c0 + (l & 3) * 64;
    unsigned orv = 0;
#pragma unroll
    for (int i = 0; i < 4; ++i) {
      uint4 v = *(const uint4*)(mp + i * 16);
      orv |= v.x | v.y | v.z | v.w;
    }
    anymask = __any(orv != 0);
  }

  bf16x8 qf0 = *(const bf16x8*)(Qbh + (q0 + lr) * HD + lk * 8);
  bf16x8 qf1 = *(const bf16x8*)(Qbh + (q0 + lr) * HD + 32 + lk * 8);

  f32x4 acc[16];
#pragma unroll
  for (int t = 0; t < 16; ++t) {
    const unsigned short* kp = Kbh + (size_t)(c0 + t * 16 + lr) * HD + lk * 8;
    bf16x8 k0 = *(const bf16x8*)kp;
    bf16x8 k1 = *(const bf16x8*)(kp + 32);
    f32x4 a = {};
    a = __builtin_amdgcn_mfma_f32_16x16x32_bf16(k0, qf0, a, 0, 0, 0);
    a = __builtin_amdgcn_mfma_f32_16x16x32_bf16(k1, qf1, a, 0, 0, 0);
    acc[t] = a;
  }

  const float sc = 0.125f;  // 1/sqrt(64)
  float m = -3e38f;
  if (anymask) {
#pragma unroll
    for (int t = 0; t < 16; ++t) {
      uchar4 m4 = *(const uchar4*)(mb + (size_t)(q0 + lr) * S_LEN + c0 + t * 16 + lk * 4);
      float v0 = m4.x ? -1e9f : acc[t][0] * sc;
      float v1 = m4.y ? -1e9f : acc[t][1] * sc;
      float v2 = m4.z ? -1e9f : acc[t][2] * sc;
      float v3 = m4.w ? -1e9f : acc[t][3] * sc;
      acc[t][0] = v0; acc[t][1] = v1; acc[t][2] = v2; acc[t][3] = v3;
      m = fmaxf(fmaxf(fmaxf(m, v0), fmaxf(v1, v2)), v3);
    }
  } else {
#pragma unroll
    for (int t = 0; t < 16; ++t) {
#pragma unroll
      for (int r = 0; r < 4; ++r) {
        float v = acc[t][r] * sc;
        acc[t][r] = v;
        m = fmaxf(m, v);
      }
    }
  }
  m = fmaxf(m, __shfl_xor(m, 16, 64));
  m = fmaxf(m, __shfl_xor(m, 32, 64));
  if (l < 16) wredmax[w][l] = m;
  __syncthreads();
  float rm = wredmax[0][lr];
#pragma unroll
  for (int ww = 1; ww < 8; ++ww) rm = fmaxf(rm, wredmax[ww][lr]);

  float s = 0.f;
#pragma unroll
  for (int t = 0; t < 16; ++t) {
#pragma unroll
    for (int r = 0; r < 4; ++r) {
      float p = __expf(acc[t][r] - rm);
      acc[t][r] = p;
      s += p;
    }
  }
  s += __shfl_xor(s, 16, 64);
  s += __shfl_xor(s, 32, 64);
  if (l < 16) wredsum[w][l] = s;
  __syncthreads();
  float tot = 0.f;
#pragma unroll
  for (int ww = 0; ww < 8; ++ww) tot += wredsum[ww][lr];
  float inv = 1.0f / tot;

  // normalized attn write (float4/lane) + pack to bf16 pairs in registers
  float* arow = attn_out + ((size_t)bh * S_LEN + q0 + lr) * S_LEN + c0;
  unsigned pk0[16], pk1[16];
#pragma unroll
  for (int t = 0; t < 16; ++t) {
    float4 o;
    o.x = acc[t][0] * inv;
    o.y = acc[t][1] * inv;
    o.z = acc[t][2] * inv;
    o.w = acc[t][3] * inv;
    *(float4*)(arow + t * 16 + lk * 4) = o;
    pk0[t] = pack2bf(o.x, o.y);
    pk1[t] = pack2bf(o.z, o.w);
  }

  // PV partial over this wave's k-slice; A-frag via cross-lane shfl.
  // Lane (lr,lk) needs P[q=lr][k = c0+ks*32+lk*8 .. +7]:
  //   tile T = 2ks+(lk>>1), source lanes lr+32*(lk&1) and +16.
  f32x4 cacc[4] = {};
#pragma unroll
  for (int ks = 0; ks < 8; ++ks) {
    const int srcA = lr + ((lk & 1) << 5);
    const int srcB = srcA + 16;
    const bool hi = lk >= 2;
    unsigned x0a = __shfl(pk0[2 * ks], srcA, 64), x0b = __shfl(pk0[2 * ks + 1], srcA, 64);
    unsigned x1a = __shfl(pk1[2 * ks], srcA, 64), x1b = __shfl(pk1[2 * ks + 1], srcA, 64);
    unsigned x2a = __shfl(pk0[2 * ks], srcB, 64), x2b = __shfl(pk0[2 * ks + 1], srcB, 64);
    unsigned x3a = __shfl(pk1[2 * ks], srcB, 64), x3b = __shfl(pk1[2 * ks + 1], srcB, 64);
    union { unsigned u[4]; bf16x8 v; } af;
    af.u[0] = hi ? x0b : x0a;
    af.u[1] = hi ? x1b : x1a;
    af.u[2] = hi ? x2b : x2a;
    af.u[3] = hi ? x3b : x3a;
#pragma unroll
    for (int dt = 0; dt < 4; ++dt) {
      bf16x8 vb = *(const bf16x8*)(Vbh + (size_t)(dt * 16 + lr) * S_LEN + c0 + ks * 32 + lk * 8);
      cacc[dt] = __builtin_amdgcn_mfma_f32_16x16x32_bf16(af.v, vb, cacc[dt], 0, 0, 0);
    }
  }
#pragma unroll
  for (int dt = 0; dt < 4; ++dt)
#pragma unroll
    for (int r = 0; r < 4; ++r)
      ctxpart[w][(lk * 4 + r) * 64 + dt * 16 + lr] = cacc[dt][r];
  __syncthreads();

  // reduce 8 partials -> ctx bf16 [B,S,1024]
  {
    int e = tid * 2;
    float2 sv = {0.f, 0.f};
#pragma unroll
    for (int ww = 0; ww < 8; ++ww) {
      float2 v = *(const float2*)&ctxpart[ww][e];
      sv.x += v.x; sv.y += v.y;
    }
    int q = e >> 6, d = e & 63;
    ushort2 o;
    o.x = f2bf(sv.x);
    o.y = f2bf(sv.y);
    *(ushort2*)&ctx[(size_t)(b * S_LEN + q0 + q) * DM + h * HD + d] = o;
  }
}

// residual + LayerNorm: out = LN(pre + Qin) * gamma + beta, rows of 1024
__global__ __launch_bounds__(256) void ln_kernel(const float* __restrict__ pre,
                                                 const float* __restrict__ Qin,
                                                 const float* __restrict__ gamma,
                                                 const float* __restrict__ beta,
                                                 float* __restrict__ out) {
  __shared__ float red[4];
  const int row = blockIdx.x;
  const int tid = threadIdx.x;
  const int wv = tid >> 6, l = tid & 63;
  const float4 a = reinterpret_cast<const float4*>(pre + (size_t)row * DM)[tid];
  const float4 q = reinterpret_cast<const float4*>(Qin + (size_t)row * DM)[tid];
  float x0 = a.x + q.x, x1 = a.y + q.y, x2 = a.z + q.z, x3 = a.w + q.w;
  float s = x0 + x1 + x2 + x3;
#pragma unroll
  for (int off = 32; off >= 1; off >>= 1) s += __shfl_xor(s, off, 64);
  if (l == 0) red[wv] = s;
  __syncthreads();
  float mean = (red[0] + red[1] + red[2] + red[3]) * (1.0f / 1024.0f);
  __syncthreads();
  float d0 = x0 - mean, d1 = x1 - mean, d2 = x2 - mean, d3 = x3 - mean;
  float s2 = d0 * d0 + d1 * d1 + d2 * d2 + d3 * d3;
#pragma unroll
  for (int off = 32; off >= 1; off >>= 1) s2 += __shfl_xor(s2, off, 64);
  if (l == 0) red[wv] = s2;
  __syncthreads();
  float var = (red[0] + red[1] + red[2] + red[3]) * (1.0f / 1024.0f);
  float rstd = rsqrtf(var + 1e-5f);
  const float4 g = reinterpret_cast<const float4*>(gamma)[tid];
  const float4 bt = reinterpret_cast<const float4*>(beta)[tid];
  float4 o;
  o.x = d0 * rstd * g.x + bt.x;
  o.y = d1 * rstd * g.y + bt.y;
  o.z = d2 * rstd * g.z + bt.z;
  o.w = d3 * rstd * g.w + bt.w;
  reinterpret_cast<float4*>(out + (size_t)row * DM)[tid] = o;
}

extern "C" void kernel_launch(void* const* d_in, const int* in_sizes, int n_in,
                              void* d_out, int out_size, void* d_ws, size_t ws_size,
                              hipStream_t stream) {
  const float* Qi = (const float*)d_in[0];
  const float* Ki = (const float*)d_in[1];
  const float* Vi = (const float*)d_in[2];
  const unsigned char* mask = (const unsigned char*)d_in[3];
  const float* Wq = (const float*)d_in[4];
  const float* bq = (const float*)d_in[5];
  const float* Wk = (const float*)d_in[6];
  const float* bk = (const float*)d_in[7];
  const float* Wv = (const float*)d_in[8];
  const float* bv = (const float*)d_in[9];
  const float* Wo = (const float*)d_in[10];
  const float* bo = (const float*)d_in[11];
  const float* gamma = (const float*)d_in[12];
  const float* beta = (const float*)d_in[13];

  char* ws = (char*)d_ws;
  unsigned short* Qb = (unsigned short*)(ws);            // [4096][1024] bf16
  unsigned short* Kb = Qb + 4194304;
  unsigned short* Vb = Qb + 2 * 4194304;
  unsigned short* Wtq = (unsigned short*)(ws + 25165824);  // [n][k] bf16 x4
  unsigned short* Wtk = Wtq + 1048576;
  unsigned short* Wtv = Wtq + 2 * 1048576;
  unsigned short* Wto = Wtq + 3 * 1048576;
  unsigned short* Qhd = (unsigned short*)(ws + 33554432);  // [B,H,S,64] bf16
  unsigned short* Khd = (unsigned short*)(ws + 41943040);  // [B,H,S,64] bf16
  unsigned short* Vtd = (unsigned short*)(ws + 50331648);  // [B,H,64,S] bf16
  unsigned short* ctx = (unsigned short*)(ws);             // reuse Qb region
  float* preLN = (float*)(ws + 8388608);                   // reuse Kb/Vb region

  float* out0 = (float*)d_out;
  float* attn = out0 + 4194304;

  cvt_kernel<<<4096, 256, 0, stream>>>(Qi, Qb);
  cvt_kernel<<<4096, 256, 0, stream>>>(Ki, Kb);
  cvt_kernel<<<4096, 256, 0, stream>>>(Vi, Vb);
  dim3 tg(32, 32);
  wtrans_kernel<<<tg, 256, 0, stream>>>(Wq, Wtq);
  wtrans_kernel<<<tg, 256, 0, stream>>>(Wk, Wtk);
  wtrans_kernel<<<tg, 256, 0, stream>>>(Wv, Wtv);
  wtrans_kernel<<<tg, 256, 0, stream>>>(Wo, Wto);
  dim3 gg(32, 8);
  gemm128<0><<<gg, 256, 0, stream>>>(Qb, Wtq, bq, Qhd);
  gemm128<0><<<gg, 256, 0, stream>>>(Kb, Wtk, bk, Khd);
  gemm128<1><<<gg, 256, 0, stream>>>(Vb, Wtv, bv, Vtd);
  dim3 ag(128, 32);
  attn_kernel<<<ag, 512, 0, stream>>>(Qhd, Khd, Vtd, mask, attn, ctx);
  gemm128<2><<<gg, 256, 0, stream>>>(ctx, Wto, bo, preLN);
  ln_kernel<<<4096, 256, 0, stream>>>(preLN, Qi, gamma, beta, out0);
}

// Round 4
// 497.407 us; speedup vs baseline: 1.2644x; 1.0210x over previous
//
#include <hip/hip_runtime.h>
#include <hip/hip_bf16.h>

#define S_LEN 2048
#define NH 16
#define HD 64
#define DM 1024

typedef float f32x4 __attribute__((ext_vector_type(4)));
typedef unsigned u32x4 __attribute__((ext_vector_type(4)));
typedef __bf16 bf16x8 __attribute__((ext_vector_type(8)));

__device__ __forceinline__ unsigned short f2bf(float f) {
  union { float f; unsigned u; } v; v.f = f;
  unsigned r = v.u + 0x7fffu + ((v.u >> 16) & 1u);
  return (unsigned short)(r >> 16);
}

__device__ __forceinline__ unsigned pack2bf(float lo, float hi) {
  return (unsigned)f2bf(lo) | ((unsigned)f2bf(hi) << 16);
}

__device__ __forceinline__ void load_lds16(const void* g, void* l) {
  __builtin_amdgcn_global_load_lds((const __attribute__((address_space(1))) void*)g,
                                   (__attribute__((address_space(3))) void*)l, 16, 0, 0);
}

// fp32 -> bf16 rowmajor convert (4 elems/thread)
__global__ __launch_bounds__(256) void cvt_kernel(const float* __restrict__ in,
                                                  unsigned short* __restrict__ out) {
  int i = blockIdx.x * 256 + threadIdx.x;
  float4 v = reinterpret_cast<const float4*>(in)[i];
  ushort4 o;
  o.x = f2bf(v.x); o.y = f2bf(v.y); o.z = f2bf(v.z); o.w = f2bf(v.w);
  reinterpret_cast<ushort4*>(out)[i] = o;
}

// W [1024][1024] fp32 -> Wt [n][k] bf16 (transpose + convert)
__global__ __launch_bounds__(256) void wtrans_kernel(const float* __restrict__ W,
                                                     unsigned short* __restrict__ Wt) {
  __shared__ float t[32][33];
  int bx = blockIdx.x * 32;  // n base
  int by = blockIdx.y * 32;  // k base
  int tx = threadIdx.x & 31, ty = threadIdx.x >> 5;
  for (int i = ty; i < 32; i += 8) t[i][tx] = W[(size_t)(by + i) * DM + bx + tx];
  __syncthreads();
  for (int i = ty; i < 32; i += 8) Wt[(size_t)(bx + i) * DM + by + tx] = f2bf(t[tx][i]);
}

// C = A[4096x1024] @ Bt[1024x1024]^T + bias.  128x128 tile, BK=32, 4 waves.
// MODE 0: bf16 head-major out [B,H,S,64]; MODE 1: bf16 transposed [B,H,64,S]; MODE 2: fp32 rowmajor.
template <int MODE>
__global__ __launch_bounds__(256) void gemm128(const unsigned short* __restrict__ A,
                                               const unsigned short* __restrict__ Bt,
                                               const float* __restrict__ bias,
                                               void* __restrict__ outp) {
  constexpr int K = 1024;
  constexpr int N = 1024;
  __shared__ unsigned short Al[128 * 32];
  __shared__ unsigned short Bl[128 * 32];
  const int tid = threadIdx.x;
  const int w = tid >> 6, l = tid & 63;
  const int m0 = blockIdx.x * 128, n0 = blockIdx.y * 128;
  const int wr = (w >> 1) * 64, wc = (w & 1) * 64;
  const int lr = l & 15, lk = l >> 4;
  f32x4 acc[4][4] = {};
  for (int kt = 0; kt < K; kt += 32) {
#pragma unroll
    for (int i = 0; i < 2; ++i) {
      int seg = i * 256 + tid;
      int row = seg >> 2, ks = (seg & 3) * 8;
      load_lds16(A + (size_t)(m0 + row) * K + kt + ks, Al + seg * 8);
      load_lds16(Bt + (size_t)(n0 + row) * K + kt + ks, Bl + seg * 8);
    }
    __syncthreads();
    bf16x8 af[4], bfr[4];
#pragma unroll
    for (int t = 0; t < 4; ++t) af[t] = *(const bf16x8*)(Al + (wr + t * 16 + lr) * 32 + lk * 8);
#pragma unroll
    for (int t = 0; t < 4; ++t) bfr[t] = *(const bf16x8*)(Bl + (wc + t * 16 + lr) * 32 + lk * 8);
#pragma unroll
    for (int i = 0; i < 4; ++i)
#pragma unroll
      for (int j = 0; j < 4; ++j)
        acc[i][j] = __builtin_amdgcn_mfma_f32_16x16x32_bf16(af[i], bfr[j], acc[i][j], 0, 0, 0);
    __syncthreads();
  }
  const int drow = lk * 4, dcol = lr;
  if (MODE == 2) {
    float* C = (float*)outp;
#pragma unroll
    for (int i = 0; i < 4; ++i)
#pragma unroll
      for (int j = 0; j < 4; ++j) {
        int n = n0 + wc + j * 16 + dcol;
        float bv = bias[n];
#pragma unroll
        for (int r = 0; r < 4; ++r) {
          int m = m0 + wr + i * 16 + drow + r;
          C[(size_t)m * N + n] = acc[i][j][r] + bv;
        }
      }
  } else if (MODE == 0) {
    unsigned short* C = (unsigned short*)outp;
#pragma unroll
    for (int i = 0; i < 4; ++i)
#pragma unroll
      for (int j = 0; j < 4; ++j) {
        int n = n0 + wc + j * 16 + dcol;
        float bv = bias[n];
        int h = n >> 6, d = n & 63;
#pragma unroll
        for (int r = 0; r < 4; ++r) {
          int m = m0 + wr + i * 16 + drow + r;
          int b = m >> 11, s = m & 2047;
          C[((size_t)(b * NH + h) * S_LEN + s) * HD + d] = f2bf(acc[i][j][r] + bv);
        }
      }
  } else {  // MODE 1: V transposed [B,H,64,S]
    unsigned short* C = (unsigned short*)outp;
#pragma unroll
    for (int i = 0; i < 4; ++i) {
      int m = m0 + wr + i * 16 + drow;  // rows m..m+3 same b (16-aligned)
      int b = m >> 11, s = m & 2047;
#pragma unroll
      for (int j = 0; j < 4; ++j) {
        int n = n0 + wc + j * 16 + dcol;
        float bv = bias[n];
        int h = n >> 6, d = n & 63;
        ushort4 o;
        o.x = f2bf(acc[i][j][0] + bv);
        o.y = f2bf(acc[i][j][1] + bv);
        o.z = f2bf(acc[i][j][2] + bv);
        o.w = f2bf(acc[i][j][3] + bv);
        *reinterpret_cast<ushort4*>(C + ((size_t)(b * NH + h) * HD + d) * S_LEN + s) = o;
      }
    }
  }
}

// Fused QK^T + softmax + attn-write + PV, swapped-operand layout, with explicit
// register double-buffered prefetch (K: 2 groups x 4 tiles; V: 2 groups x 4 rows,
// issued before softmax) and non-temporal attn stores (keep K/V L2-resident).
#define LOADK(BUF, G)                                                                    \
  _Pragma("unroll") for (int t4 = 0; t4 < 4; ++t4) {                                     \
    const unsigned short* kp = Kbh + (size_t)(c0 + ((G) * 4 + t4) * 16 + lr) * HD + lk * 8; \
    BUF[t4][0] = *(const bf16x8*)kp;                                                     \
    BUF[t4][1] = *(const bf16x8*)(kp + 32);                                              \
  }

#define MFMAK(BUF, G)                                                                    \
  _Pragma("unroll") for (int t4 = 0; t4 < 4; ++t4) {                                     \
    f32x4 a = {};                                                                        \
    a = __builtin_amdgcn_mfma_f32_16x16x32_bf16(BUF[t4][0], qf0, a, 0, 0, 0);            \
    a = __builtin_amdgcn_mfma_f32_16x16x32_bf16(BUF[t4][1], qf1, a, 0, 0, 0);            \
    acc[(G) * 4 + t4] = a;                                                               \
  }

#define LOADV(BUF, KS)                                                                   \
  _Pragma("unroll") for (int dt = 0; dt < 4; ++dt)                                       \
      BUF[dt] = *(const bf16x8*)(Vbh + (size_t)(dt * 16 + lr) * S_LEN + c0 + (KS) * 32 + lk * 8);

#define PVSTEP(BUF, KS)                                                                  \
  {                                                                                      \
    unsigned x0a = __shfl(pk0[2 * (KS)], srcA, 64), x0b = __shfl(pk0[2 * (KS) + 1], srcA, 64); \
    unsigned x1a = __shfl(pk1[2 * (KS)], srcA, 64), x1b = __shfl(pk1[2 * (KS) + 1], srcA, 64); \
    unsigned x2a = __shfl(pk0[2 * (KS)], srcB, 64), x2b = __shfl(pk0[2 * (KS) + 1], srcB, 64); \
    unsigned x3a = __shfl(pk1[2 * (KS)], srcB, 64), x3b = __shfl(pk1[2 * (KS) + 1], srcB, 64); \
    union { unsigned u[4]; bf16x8 v; } af;                                               \
    af.u[0] = hi ? x0b : x0a;                                                            \
    af.u[1] = hi ? x1b : x1a;                                                            \
    af.u[2] = hi ? x2b : x2a;                                                            \
    af.u[3] = hi ? x3b : x3a;                                                            \
    _Pragma("unroll") for (int dt = 0; dt < 4; ++dt)                                     \
        cacc[dt] = __builtin_amdgcn_mfma_f32_16x16x32_bf16(af.v, BUF[dt], cacc[dt], 0, 0, 0); \
  }

__global__ __launch_bounds__(512, 3) void attn_kernel(const unsigned short* __restrict__ Qh,
                                                      const unsigned short* __restrict__ Kh,
                                                      const unsigned short* __restrict__ Vt,
                                                      const unsigned char* __restrict__ mask,
                                                      float* __restrict__ attn_out,
                                                      unsigned short* __restrict__ ctx) {
  __shared__ float wredmax[8][16];
  __shared__ float wredsum[8][16];
  __shared__ float ctxpart[8][16][68];  // padded row: 68 floats -> conflict-free
  const int tid = threadIdx.x;
  const int w = tid >> 6, l = tid & 63;
  const int lr = l & 15, lk = l >> 4;
  const int q0 = blockIdx.x * 16;
  const int bh = blockIdx.y;
  const int b = bh >> 4, h = bh & 15;
  const int c0 = w * 256;
  const unsigned short* Qbh = Qh + (size_t)bh * S_LEN * HD;
  const unsigned short* Kbh = Kh + (size_t)bh * S_LEN * HD;
  const unsigned short* Vbh = Vt + (size_t)bh * HD * S_LEN;
  const unsigned char* mb = mask + (size_t)b * S_LEN * S_LEN;

  // wave-level mask fast-path check on [q0,q0+16) x [c0,c0+256) (non-temporal)
  unsigned orv = 0;
  {
    const unsigned char* mp = mb + (size_t)(q0 + (l >> 2)) * S_LEN + c0 + (l & 3) * 64;
#pragma unroll
    for (int i = 0; i < 4; ++i) {
      u32x4 v = __builtin_nontemporal_load((const u32x4*)(mp + i * 16));
      orv |= v.x | v.y | v.z | v.w;
    }
  }

  bf16x8 qf0 = *(const bf16x8*)(Qbh + (q0 + lr) * HD + lk * 8);
  bf16x8 qf1 = *(const bf16x8*)(Qbh + (q0 + lr) * HD + 32 + lk * 8);

  f32x4 acc[16];
  bf16x8 kA[4][2], kB[4][2];
  LOADK(kA, 0)
  LOADK(kB, 1)
  MFMAK(kA, 0)
  LOADK(kA, 2)
  MFMAK(kB, 1)
  LOADK(kB, 3)
  MFMAK(kA, 2)
  MFMAK(kB, 3)

  // prefetch first two V groups; latency hides under softmax VALU work
  bf16x8 vA[4], vB[4];
  LOADV(vA, 0)
  LOADV(vB, 1)

  const int anymask = __any(orv != 0);
  const float sc = 0.125f;  // 1/sqrt(64)
  float m = -3e38f;
  if (anymask) {
#pragma unroll
    for (int t = 0; t < 16; ++t) {
      uchar4 m4 = *(const uchar4*)(mb + (size_t)(q0 + lr) * S_LEN + c0 + t * 16 + lk * 4);
      float v0 = m4.x ? -1e9f : acc[t][0] * sc;
      float v1 = m4.y ? -1e9f : acc[t][1] * sc;
      float v2 = m4.z ? -1e9f : acc[t][2] * sc;
      float v3 = m4.w ? -1e9f : acc[t][3] * sc;
      acc[t][0] = v0; acc[t][1] = v1; acc[t][2] = v2; acc[t][3] = v3;
      m = fmaxf(fmaxf(fmaxf(m, v0), fmaxf(v1, v2)), v3);
    }
  } else {
#pragma unroll
    for (int t = 0; t < 16; ++t) {
#pragma unroll
      for (int r = 0; r < 4; ++r) {
        float v = acc[t][r] * sc;
        acc[t][r] = v;
        m = fmaxf(m, v);
      }
    }
  }
  m = fmaxf(m, __shfl_xor(m, 16, 64));
  m = fmaxf(m, __shfl_xor(m, 32, 64));
  if (l < 16) wredmax[w][l] = m;
  __syncthreads();
  float rm = wredmax[0][lr];
#pragma unroll
  for (int ww = 1; ww < 8; ++ww) rm = fmaxf(rm, wredmax[ww][lr]);

  float s = 0.f;
#pragma unroll
  for (int t = 0; t < 16; ++t) {
#pragma unroll
    for (int r = 0; r < 4; ++r) {
      float p = __expf(acc[t][r] - rm);
      acc[t][r] = p;
      s += p;
    }
  }
  s += __shfl_xor(s, 16, 64);
  s += __shfl_xor(s, 32, 64);
  if (l < 16) wredsum[w][l] = s;
  __syncthreads();
  float tot = 0.f;
#pragma unroll
  for (int ww = 0; ww < 8; ++ww) tot += wredsum[ww][lr];
  float inv = 1.0f / tot;

  // normalized attn write (non-temporal f32x4/lane) + pack bf16 pairs
  float* arow = attn_out + ((size_t)bh * S_LEN + q0 + lr) * S_LEN + c0;
  unsigned pk0[16], pk1[16];
#pragma unroll
  for (int t = 0; t < 16; ++t) {
    f32x4 o;
    o.x = acc[t][0] * inv;
    o.y = acc[t][1] * inv;
    o.z = acc[t][2] * inv;
    o.w = acc[t][3] * inv;
    __builtin_nontemporal_store(o, (f32x4*)(arow + t * 16 + lk * 4));
    pk0[t] = pack2bf(o.x, o.y);
    pk1[t] = pack2bf(o.z, o.w);
  }

  // PV partial over this wave's k-slice; A-frag via cross-lane shfl,
  // V double-buffered in registers.
  const int srcA = lr + ((lk & 1) << 5);
  const int srcB = srcA + 16;
  const bool hi = lk >= 2;
  f32x4 cacc[4] = {};
  PVSTEP(vA, 0) LOADV(vA, 2)
  PVSTEP(vB, 1) LOADV(vB, 3)
  PVSTEP(vA, 2) LOADV(vA, 4)
  PVSTEP(vB, 3) LOADV(vB, 5)
  PVSTEP(vA, 4) LOADV(vA, 6)
  PVSTEP(vB, 5) LOADV(vB, 7)
  PVSTEP(vA, 6)
  PVSTEP(vB, 7)
#pragma unroll
  for (int dt = 0; dt < 4; ++dt)
#pragma unroll
    for (int r = 0; r < 4; ++r)
      ctxpart[w][lk * 4 + r][dt * 16 + lr] = cacc[dt][r];
  __syncthreads();

  // reduce 8 partials -> ctx bf16 [B,S,1024]
  {
    int e = tid * 2;
    int q = e >> 6, d = e & 63;
    float2 sv = {0.f, 0.f};
#pragma unroll
    for (int ww = 0; ww < 8; ++ww) {
      float2 v = *(const float2*)&ctxpart[ww][q][d];
      sv.x += v.x; sv.y += v.y;
    }
    ushort2 o;
    o.x = f2bf(sv.x);
    o.y = f2bf(sv.y);
    *(ushort2*)&ctx[(size_t)(b * S_LEN + q0 + q) * DM + h * HD + d] = o;
  }
}

// residual + LayerNorm: out = LN(pre + Qin) * gamma + beta, rows of 1024
__global__ __launch_bounds__(256) void ln_kernel(const float* __restrict__ pre,
                                                 const float* __restrict__ Qin,
                                                 const float* __restrict__ gamma,
                                                 const float* __restrict__ beta,
                                                 float* __restrict__ out) {
  __shared__ float red[4];
  const int row = blockIdx.x;
  const int tid = threadIdx.x;
  const int wv = tid >> 6, l = tid & 63;
  const float4 a = reinterpret_cast<const float4*>(pre + (size_t)row * DM)[tid];
  const float4 q = reinterpret_cast<const float4*>(Qin + (size_t)row * DM)[tid];
  float x0 = a.x + q.x, x1 = a.y + q.y, x2 = a.z + q.z, x3 = a.w + q.w;
  float s = x0 + x1 + x2 + x3;
#pragma unroll
  for (int off = 32; off >= 1; off >>= 1) s += __shfl_xor(s, off, 64);
  if (l == 0) red[wv] = s;
  __syncthreads();
  float mean = (red[0] + red[1] + red[2] + red[3]) * (1.0f / 1024.0f);
  __syncthreads();
  float d0 = x0 - mean, d1 = x1 - mean, d2 = x2 - mean, d3 = x3 - mean;
  float s2 = d0 * d0 + d1 * d1 + d2 * d2 + d3 * d3;
#pragma unroll
  for (int off = 32; off >= 1; off >>= 1) s2 += __shfl_xor(s2, off, 64);
  if (l == 0) red[wv] = s2;
  __syncthreads();
  float var = (red[0] + red[1] + red[2] + red[3]) * (1.0f / 1024.0f);
  float rstd = rsqrtf(var + 1e-5f);
  const float4 g = reinterpret_cast<const float4*>(gamma)[tid];
  const float4 bt = reinterpret_cast<const float4*>(beta)[tid];
  float4 o;
  o.x = d0 * rstd * g.x + bt.x;
  o.y = d1 * rstd * g.y + bt.y;
  o.z = d2 * rstd * g.z + bt.z;
  o.w = d3 * rstd * g.w + bt.w;
  reinterpret_cast<float4*>(out + (size_t)row * DM)[tid] = o;
}

extern "C" void kernel_launch(void* const* d_in, const int* in_sizes, int n_in,
                              void* d_out, int out_size, void* d_ws, size_t ws_size,
                              hipStream_t stream) {
  const float* Qi = (const float*)d_in[0];
  const float* Ki = (const float*)d_in[1];
  const float* Vi = (const float*)d_in[2];
  const unsigned char* mask = (const unsigned char*)d_in[3];
  const float* Wq = (const float*)d_in[4];
  const float* bq = (const float*)d_in[5];
  const float* Wk = (const float*)d_in[6];
  const float* bk = (const float*)d_in[7];
  const float* Wv = (const float*)d_in[8];
  const float* bv = (const float*)d_in[9];
  const float* Wo = (const float*)d_in[10];
  const float* bo = (const float*)d_in[11];
  const float* gamma = (const float*)d_in[12];
  const float* beta = (const float*)d_in[13];

  char* ws = (char*)d_ws;
  unsigned short* Qb = (unsigned short*)(ws);            // [4096][1024] bf16
  unsigned short* Kb = Qb + 4194304;
  unsigned short* Vb = Qb + 2 * 4194304;
  unsigned short* Wtq = (unsigned short*)(ws + 25165824);  // [n][k] bf16 x4
  unsigned short* Wtk = Wtq + 1048576;
  unsigned short* Wtv = Wtq + 2 * 1048576;
  unsigned short* Wto = Wtq + 3 * 1048576;
  unsigned short* Qhd = (unsigned short*)(ws + 33554432);  // [B,H,S,64] bf16
  unsigned short* Khd = (unsigned short*)(ws + 41943040);  // [B,H,S,64] bf16
  unsigned short* Vtd = (unsigned short*)(ws + 50331648);  // [B,H,64,S] bf16
  unsigned short* ctx = (unsigned short*)(ws);             // reuse Qb region
  float* preLN = (float*)(ws + 8388608);                   // reuse Kb/Vb region

  float* out0 = (float*)d_out;
  float* attn = out0 + 4194304;

  cvt_kernel<<<4096, 256, 0, stream>>>(Qi, Qb);
  cvt_kernel<<<4096, 256, 0, stream>>>(Ki, Kb);
  cvt_kernel<<<4096, 256, 0, stream>>>(Vi, Vb);
  dim3 tg(32, 32);
  wtrans_kernel<<<tg, 256, 0, stream>>>(Wq, Wtq);
  wtrans_kernel<<<tg, 256, 0, stream>>>(Wk, Wtk);
  wtrans_kernel<<<tg, 256, 0, stream>>>(Wv, Wtv);
  wtrans_kernel<<<tg, 256, 0, stream>>>(Wo, Wto);
  dim3 gg(32, 8);
  gemm128<0><<<gg, 256, 0, stream>>>(Qb, Wtq, bq, Qhd);
  gemm128<0><<<gg, 256, 0, stream>>>(Kb, Wtk, bk, Khd);
  gemm128<1><<<gg, 256, 0, stream>>>(Vb, Wtv, bv, Vtd);
  dim3 ag(128, 32);
  attn_kernel<<<ag, 512, 0, stream>>>(Qhd, Khd, Vtd, mask, attn, ctx);
  gemm128<2><<<gg, 256, 0, stream>>>(ctx, Wto, bo, preLN);
  ln_kernel<<<4096, 256, 0, stream>>>(preLN, Qi, gamma, beta, out0);
}